// Round 1
// baseline (164.209 us; speedup 1.0000x reference)
//
#include <hip/hip_runtime.h>
#include <hip/hip_bf16.h>

// ---------------------------------------------------------------------------
// FactorizedAttention  (N=32, T=50, LQ=LK=64, E=128, H=8, d=16)
// out0: (N,T,LQ,E) f32 = 13107200 elems
// out1: attn (H,N,T,LQ,LK) f32 = 52428800 elems
// ---------------------------------------------------------------------------

#define NB   32
#define TT   50
#define LL   64
#define EE   128
#define HH   8
#define DD   16
#define NBT  (NB * TT)            // 1600 (b,T) tiles
#define MTOT (NBT * LL)           // 102400 rows
#define OUT0_ELEMS 13107200L
#define ATTN_PER_BT 4096L         // 64*64

typedef __attribute__((ext_vector_type(8))) short bf16x8;
typedef __attribute__((ext_vector_type(4))) float f32x4;
typedef __attribute__((ext_vector_type(4))) unsigned short u16x4;

__device__ __forceinline__ unsigned short f2b(float f) {
  union { float f; unsigned u; } v; v.f = f;
  unsigned r = v.u + 0x7FFFu + ((v.u >> 16) & 1u);
  return (unsigned short)(r >> 16);
}
__device__ __forceinline__ float b2f(unsigned short s) {
  union { unsigned u; float f; } v; v.u = ((unsigned)s) << 16;
  return v.f;
}
__device__ __forceinline__ bf16x8 zero8() {
  bf16x8 z;
  #pragma unroll
  for (int i = 0; i < 8; ++i) z[i] = 0;
  return z;
}

// ---------------------------------------------------------------------------
// Mask dtype detector: bool may arrive as int32 words (0/1), raw bytes (0/1),
// or f32 (0.0/1.0). Classify deterministically from the first 4096 bytes.
// mode 0 = int32, 1 = bytes, 2 = f32
// ---------------------------------------------------------------------------
__global__ void detect_mask_mode(const unsigned char* __restrict__ p,
                                 int* __restrict__ flag) {
  __shared__ int sb, sf;
  int t = threadIdx.x;
  if (t == 0) { sb = 0; sf = 0; }
  __syncthreads();
  int bnz = 0, fcnt = 0;
  for (int i = t * 16; i < t * 16 + 16; ++i)
    if ((i & 3) && p[i]) bnz++;
  const unsigned int* w = (const unsigned int*)p;
  for (int i = t * 4; i < t * 4 + 4; ++i)
    if (w[i] == 0x3f800000u) fcnt++;
  if (bnz) atomicAdd(&sb, 1);
  if (fcnt) atomicAdd(&sf, 1);
  __syncthreads();
  if (t == 0) *flag = sf ? 2 : (sb ? 1 : 0);
}

// ---------------------------------------------------------------------------
// Projection GEMM: Y = X @ W^T + bias, optional scale. M-tile = 64, N = K = 128.
// TIn = float  -> X row-major (global inputs)
// TIn = ushort -> X is bf16 head-major [bT][h][l][d] (K3 path)
// OUT_HM: write bf16 head-major to ws; else f32 row-major (final output)
// ---------------------------------------------------------------------------
template <typename TIn, bool OUT_HM>
__global__ __launch_bounds__(256) void proj_kernel(
    const TIn* __restrict__ X, const float* __restrict__ W,
    const float* __restrict__ bias, void* __restrict__ Yv, float scale) {
  __shared__ unsigned short As[64][136];
  __shared__ unsigned short Bs[128][136];
  const int tid = threadIdx.x;
  const long mBase = (long)blockIdx.x * 64;

  // ---- stage A tile (64 x 128) into LDS as bf16
  if constexpr (sizeof(TIn) == 4) {  // fp32 row-major input
    #pragma unroll
    for (int it = 0; it < 8; ++it) {
      int flat = it * 1024 + tid * 4;
      int r = flat >> 7, c = flat & 127;
      float4 v = *(const float4*)((const float*)X + mBase * 128 + flat);
      As[r][c + 0] = f2b(v.x); As[r][c + 1] = f2b(v.y);
      As[r][c + 2] = f2b(v.z); As[r][c + 3] = f2b(v.w);
    }
  } else {  // bf16 head-major input: elem (row,e) at ((bT*8+e/16)*64+l)*16+e%16
    const long bT = blockIdx.x;  // 64-row tiles align with (b,T) groups
    #pragma unroll
    for (int it = 0; it < 4; ++it) {
      int flat = it * 2048 + tid * 8;
      int r = flat >> 7, c = flat & 127;
      bf16x8 v = *(const bf16x8*)((const unsigned short*)X +
                                  ((bT * 8 + (c >> 4)) * 64 + r) * 16 + (c & 15));
      *(bf16x8*)&As[r][c] = v;
    }
  }
  // ---- stage W (128 x 128 f32) into LDS as bf16
  #pragma unroll
  for (int it = 0; it < 16; ++it) {
    int flat = it * 1024 + tid * 4;
    int r = flat >> 7, c = flat & 127;
    float4 v = *(const float4*)(W + flat);
    Bs[r][c + 0] = f2b(v.x); Bs[r][c + 1] = f2b(v.y);
    Bs[r][c + 2] = f2b(v.z); Bs[r][c + 3] = f2b(v.w);
  }
  __syncthreads();

  const int lane = tid & 63, wv = tid >> 6;
  const int ln = lane & 15, g = lane >> 4;
  const int nBase = wv * 32;

  f32x4 acc[4][2] = {};
  #pragma unroll
  for (int ks = 0; ks < 4; ++ks) {
    bf16x8 a[4], b[2];
    #pragma unroll
    for (int ms = 0; ms < 4; ++ms)
      a[ms] = *(const bf16x8*)&As[ms * 16 + ln][ks * 32 + 8 * g];
    #pragma unroll
    for (int ns = 0; ns < 2; ++ns)
      b[ns] = *(const bf16x8*)&Bs[nBase + ns * 16 + ln][ks * 32 + 8 * g];
    #pragma unroll
    for (int ms = 0; ms < 4; ++ms)
      #pragma unroll
      for (int ns = 0; ns < 2; ++ns)
        acc[ms][ns] = __builtin_amdgcn_mfma_f32_16x16x32_bf16(
            a[ms], b[ns], acc[ms][ns], 0, 0, 0);
  }

  // ---- epilogue: D layout col=lane&15, row=(lane>>4)*4+reg
  #pragma unroll
  for (int ms = 0; ms < 4; ++ms) {
    #pragma unroll
    for (int ns = 0; ns < 2; ++ns) {
      int n = nBase + ns * 16 + ln;
      float bvv = bias[n];
      #pragma unroll
      for (int r = 0; r < 4; ++r) {
        long row = mBase + ms * 16 + 4 * g + r;
        float val = (acc[ms][ns][r] + bvv) * scale;
        if constexpr (OUT_HM) {
          unsigned short* Y = (unsigned short*)Yv;
          long bT = row >> 6; int l = (int)(row & 63);
          Y[((bT * 8 + (n >> 4)) * 64 + l) * 16 + (n & 15)] = f2b(val);
        } else {
          ((float*)Yv)[row * 128 + n] = val;
        }
      }
    }
  }
}

// ---------------------------------------------------------------------------
// Attention: one wave per (b,T,h). Swapped QK^T (mfma(K,Q)) so softmax over t
// is 16 in-lane values + shfl_xor(16,32). P -> LDS bf16 -> coalesced f32
// global write + PV MFMAs.
// ---------------------------------------------------------------------------
__global__ __launch_bounds__(64) void attn_kernel(
    const unsigned short* __restrict__ qp, const unsigned short* __restrict__ kp,
    const unsigned short* __restrict__ vp, const unsigned char* __restrict__ maskp,
    const int* __restrict__ modeFlag, unsigned short* __restrict__ oh,
    float* __restrict__ attn_out) {
  __shared__ unsigned short Ksh[64][24];
  __shared__ unsigned short Qsh[64][24];
  __shared__ unsigned short Vt[16][72];
  __shared__ unsigned short Ps[64][72];
  __shared__ float maskS[64];

  const int bid = blockIdx.x;
  const int h = bid & 7;
  const int bT = bid >> 3;  // 0..1599
  const int lane = threadIdx.x;
  const int ln = lane & 15, g = lane >> 4;

  const long hbase = ((long)bT * 8 + h) * 64 * 16;  // [bT][h][0][0] in head-major

  {  // load Q,K rows; V transposed; mask
    const bf16x8* qs = (const bf16x8*)(qp + hbase + (long)lane * 16);
    *(bf16x8*)&Qsh[lane][0] = qs[0];
    *(bf16x8*)&Qsh[lane][8] = qs[1];
    const bf16x8* ks = (const bf16x8*)(kp + hbase + (long)lane * 16);
    *(bf16x8*)&Ksh[lane][0] = ks[0];
    *(bf16x8*)&Ksh[lane][8] = ks[1];
    const bf16x8* vs = (const bf16x8*)(vp + hbase + (long)lane * 16);
    unsigned short vr[16];
    *(bf16x8*)&vr[0] = vs[0];
    *(bf16x8*)&vr[8] = vs[1];
    #pragma unroll
    for (int d = 0; d < 16; ++d) Vt[d][lane] = vr[d];

    int mode = *modeFlag;
    long midx = (long)bT * 64 + lane;
    bool mk;
    if (mode == 0)      mk = ((const int*)maskp)[midx] != 0;
    else if (mode == 1) mk = maskp[midx] != 0;
    else                mk = ((const float*)maskp)[midx] != 0.0f;
    maskS[lane] = mk ? -INFINITY : 0.0f;
  }
  __syncthreads();

  // QK^T swapped: s[tsub][lsub]; D: col(ln)=l_local, row(4g+r)=t_local
  f32x4 s[4][4] = {};
  {
    bf16x8 z = zero8();
    bf16x8 aK[4], bQ[4];
    #pragma unroll
    for (int i = 0; i < 4; ++i) {
      aK[i] = (g < 2) ? *(const bf16x8*)&Ksh[i * 16 + ln][8 * g] : z;
      bQ[i] = (g < 2) ? *(const bf16x8*)&Qsh[i * 16 + ln][8 * g] : z;
    }
    #pragma unroll
    for (int t = 0; t < 4; ++t)
      #pragma unroll
      for (int l = 0; l < 4; ++l)
        s[t][l] = __builtin_amdgcn_mfma_f32_16x16x32_bf16(aK[t], bQ[l], s[t][l],
                                                          0, 0, 0);
  }

  float mv[4][4];
  #pragma unroll
  for (int t = 0; t < 4; ++t)
    #pragma unroll
    for (int r = 0; r < 4; ++r) mv[t][r] = maskS[t * 16 + 4 * g + r];

  // softmax over t for each of the 4 l-subtiles this lane's column belongs to
  #pragma unroll
  for (int l = 0; l < 4; ++l) {
    float m = -INFINITY;
    #pragma unroll
    for (int t = 0; t < 4; ++t)
      #pragma unroll
      for (int r = 0; r < 4; ++r) {
        float sv = s[t][l][r] + mv[t][r];
        s[t][l][r] = sv;
        m = fmaxf(m, sv);
      }
    m = fmaxf(m, __shfl_xor(m, 16, 64));
    m = fmaxf(m, __shfl_xor(m, 32, 64));
    float sum = 0.f;
    #pragma unroll
    for (int t = 0; t < 4; ++t)
      #pragma unroll
      for (int r = 0; r < 4; ++r) {
        float p = (m == -INFINITY) ? 0.f : __expf(s[t][l][r] - m);
        s[t][l][r] = p;
        sum += p;
      }
    sum += __shfl_xor(sum, 16, 64);
    sum += __shfl_xor(sum, 32, 64);
    float inv = (sum > 0.f) ? 1.f / sum : 0.f;
    #pragma unroll
    for (int t = 0; t < 4; ++t)
      #pragma unroll
      for (int r = 0; r < 4; ++r) s[t][l][r] *= inv;
  }

  // P -> LDS (bf16), row = l, col = t
  #pragma unroll
  for (int t = 0; t < 4; ++t)
    #pragma unroll
    for (int l = 0; l < 4; ++l) {
      u16x4 w;
      w[0] = f2b(s[t][l][0]); w[1] = f2b(s[t][l][1]);
      w[2] = f2b(s[t][l][2]); w[3] = f2b(s[t][l][3]);
      *(u16x4*)&Ps[l * 16 + ln][t * 16 + 4 * g] = w;
    }
  __syncthreads();

  // coalesced attn output write: (h,b,T,l,t) f32
  const long abase = ((long)h * NBT + bT) * ATTN_PER_BT;
  #pragma unroll
  for (int it = 0; it < 16; ++it) {
    int row = it * 4 + g;
    u16x4 pv = *(const u16x4*)&Ps[row][4 * ln];
    float4 o = make_float4(b2f(pv[0]), b2f(pv[1]), b2f(pv[2]), b2f(pv[3]));
    *(float4*)&attn_out[abase + (long)row * 64 + 4 * ln] = o;
  }

  // PV: O[l][d] = sum_t P[l][t] V[t][d]
  f32x4 oacc[4] = {};
  #pragma unroll
  for (int ks = 0; ks < 2; ++ks) {
    bf16x8 bV = *(const bf16x8*)&Vt[ln][ks * 32 + 8 * g];
    #pragma unroll
    for (int l = 0; l < 4; ++l) {
      bf16x8 aP = *(const bf16x8*)&Ps[l * 16 + ln][ks * 32 + 8 * g];
      oacc[l] = __builtin_amdgcn_mfma_f32_16x16x32_bf16(aP, bV, oacc[l], 0, 0, 0);
    }
  }
  // store head output bf16 head-major: col(ln)=d, row=4g+r within l-subtile
  #pragma unroll
  for (int l = 0; l < 4; ++l)
    #pragma unroll
    for (int r = 0; r < 4; ++r) {
      int lrow = l * 16 + 4 * g + r;
      oh[hbase + (long)lrow * 16 + ln] = f2b(oacc[l][r]);
    }
}

// ---------------------------------------------------------------------------
extern "C" void kernel_launch(void* const* d_in, const int* in_sizes, int n_in,
                              void* d_out, int out_size, void* d_ws,
                              size_t ws_size, hipStream_t stream) {
  (void)in_sizes; (void)n_in; (void)out_size; (void)ws_size;
  const float* query = (const float*)d_in[0];
  const float* key   = (const float*)d_in[1];
  const float* value = (const float*)d_in[2];
  const unsigned char* mask = (const unsigned char*)d_in[3];
  const float* Wq = (const float*)d_in[4];
  const float* bq = (const float*)d_in[5];
  const float* Wk = (const float*)d_in[6];
  const float* bk = (const float*)d_in[7];
  const float* Wv = (const float*)d_in[8];
  const float* bv = (const float*)d_in[9];
  const float* Wo = (const float*)d_in[10];
  const float* bo = (const float*)d_in[11];

  float* out0 = (float*)d_out;
  float* attn_out = out0 + OUT0_ELEMS;

  char* ws = (char*)d_ws;
  int* flag = (int*)ws;
  unsigned short* qp = (unsigned short*)(ws + 256);
  unsigned short* kp = qp + OUT0_ELEMS;
  unsigned short* vp = kp + OUT0_ELEMS;
  unsigned short* oh = vp + OUT0_ELEMS;

  detect_mask_mode<<<1, 256, 0, stream>>>(mask, flag);

  proj_kernel<float, true><<<NBT, 256, 0, stream>>>(query, Wq, bq, qp, 0.25f);
  proj_kernel<float, true><<<NBT, 256, 0, stream>>>(key,   Wk, bk, kp, 1.0f);
  proj_kernel<float, true><<<NBT, 256, 0, stream>>>(value, Wv, bv, vp, 1.0f);

  attn_kernel<<<NBT * HH, 64, 0, stream>>>(qp, kp, vp, mask, flag, oh, attn_out);

  proj_kernel<unsigned short, false><<<NBT, 256, 0, stream>>>(oh, Wo, bo, out0,
                                                              1.0f);
}

// Round 2
// 137.998 us; speedup vs baseline: 1.1899x; 1.1899x over previous
//
#include <hip/hip_runtime.h>
#include <hip/hip_bf16.h>

// ---------------------------------------------------------------------------
// FactorizedAttention fused (N=32, T=50, LQ=LK=64, E=128, H=8, d=16)
// One block per (b,T) tile: QKV proj -> attention -> O proj, all in LDS.
// out0: (N,T,LQ,E) f32 = 13107200 ; out1: attn (H,N,T,LQ,LK) f32 = 52428800
// ---------------------------------------------------------------------------

#define NBT 1600
#define OUT0_ELEMS 13107200L

typedef __attribute__((ext_vector_type(8))) short bf16x8;
typedef __attribute__((ext_vector_type(4))) float f32x4;
typedef __attribute__((ext_vector_type(4))) unsigned short u16x4;

__device__ __forceinline__ unsigned short f2b(float f) {
  union { float f; unsigned u; } v; v.f = f;
  unsigned r = v.u + 0x7FFFu + ((v.u >> 16) & 1u);
  return (unsigned short)(r >> 16);
}
__device__ __forceinline__ float b2f(unsigned short s) {
  union { unsigned u; float f; } v; v.u = ((unsigned)s) << 16;
  return v.f;
}
__device__ __forceinline__ bf16x8 zero8() {
  bf16x8 z;
  #pragma unroll
  for (int i = 0; i < 8; ++i) z[i] = 0;
  return z;
}

// ---------------------------------------------------------------------------
// Mask dtype detector (bool as int32 / bytes / f32). mode 0=int32,1=bytes,2=f32
// ---------------------------------------------------------------------------
__global__ void detect_mask_mode(const unsigned char* __restrict__ p,
                                 int* __restrict__ flag) {
  __shared__ int sb, sf;
  int t = threadIdx.x;
  if (t == 0) { sb = 0; sf = 0; }
  __syncthreads();
  int bnz = 0, fcnt = 0;
  for (int i = t * 16; i < t * 16 + 16; ++i)
    if ((i & 3) && p[i]) bnz++;
  const unsigned int* w = (const unsigned int*)p;
  for (int i = t * 4; i < t * 4 + 4; ++i)
    if (w[i] == 0x3f800000u) fcnt++;
  if (bnz) atomicAdd(&sb, 1);
  if (fcnt) atomicAdd(&sf, 1);
  __syncthreads();
  if (t == 0) *flag = sf ? 2 : (sb ? 1 : 0);
}

// ---------------------------------------------------------------------------
// Weights -> bf16 once (softmax scale 0.25 folded into Wq; exact, pow2).
// wall layout: [0]=Wq*0.25, [1]=Wk, [2]=Wv, [3]=Wo, each 16384 bf16.
// ---------------------------------------------------------------------------
__global__ void prep_weights(const float* __restrict__ Wq,
                             const float* __restrict__ Wk,
                             const float* __restrict__ Wv,
                             const float* __restrict__ Wo,
                             unsigned short* __restrict__ wall) {
  int idx = blockIdx.x * 256 + threadIdx.x;  // grid 256 -> 65536
  int m = idx >> 14, j = idx & 16383;
  const float* src = (m == 0) ? Wq : (m == 1) ? Wk : (m == 2) ? Wv : Wo;
  float s = (m == 0) ? 0.25f : 1.0f;
  wall[idx] = f2b(src[j] * s);
}

// ---------------------------------------------------------------------------
// Fused kernel: 1600 blocks x 512 threads (8 waves; wave w = head w).
// ---------------------------------------------------------------------------
__global__ __launch_bounds__(512, 2) void fused_kernel(
    const float* __restrict__ q_in, const float* __restrict__ k_in,
    const float* __restrict__ v_in, const unsigned char* __restrict__ maskp,
    const int* __restrict__ modeFlag, const unsigned short* __restrict__ wall,
    const float* __restrict__ bq, const float* __restrict__ bk,
    const float* __restrict__ bv, const float* __restrict__ bo,
    float* __restrict__ out0, float* __restrict__ attn_out) {
  __shared__ __align__(16) unsigned short Ksh[8][64][24];   // 24576 B
  __shared__ __align__(16) unsigned short Vt[8][16][72];    // 18432 B
  __shared__ float maskS[64];                               //   256 B
  __shared__ __align__(16) unsigned short Qbuf[8 * 64 * 24];  // 24576: Qsh|Oh
  __shared__ __align__(16) unsigned short Bbuf[8 * 64 * 72];  // 73728: Ps|Xs

  auto Qsh = (unsigned short(*)[64][24])Qbuf;  // [8][64][24]
  auto Oh  = (unsigned short(*)[136])Qbuf;     // [64][136] (17408 B fits)
  auto Ps  = (unsigned short(*)[64][72])Bbuf;  // [8][64][72]
  auto Xs  = (unsigned short(*)[136])Bbuf;     // [64][136] (17408 B fits)

  const int tid = threadIdx.x;
  const int w = tid >> 6;           // wave = head
  const int lane = tid & 63;
  const int ln = lane & 15, g = lane >> 4;
  const long bT = blockIdx.x;

  // mask -> additive bias in LDS
  if (tid < 64) {
    int mode = *modeFlag;
    long midx = bT * 64 + tid;
    bool mk;
    if (mode == 0)      mk = ((const int*)maskp)[midx] != 0;
    else if (mode == 1) mk = maskp[midx] != 0;
    else                mk = ((const float*)maskp)[midx] != 0.0f;
    maskS[tid] = mk ? -INFINITY : 0.0f;
  }

  // prefetch the three 64x128 f32 X tiles into registers (4 float4 each)
  float4 xr[3][4];
  {
    const float* xs0 = q_in + bT * 8192;
    const float* xs1 = k_in + bT * 8192;
    const float* xs2 = v_in + bT * 8192;
    #pragma unroll
    for (int it = 0; it < 4; ++it) {
      int flat = it * 2048 + tid * 4;
      xr[0][it] = *(const float4*)(xs0 + flat);
      xr[1][it] = *(const float4*)(xs1 + flat);
      xr[2][it] = *(const float4*)(xs2 + flat);
    }
  }

  // ---- QKV projections: Y[:,16w..16w+16) per wave ----
  #pragma unroll
  for (int t3 = 0; t3 < 3; ++t3) {
    #pragma unroll
    for (int it = 0; it < 4; ++it) {
      int flat = it * 2048 + tid * 4;
      int r = flat >> 7, c = flat & 127;
      float4 xv = xr[t3][it];
      u16x4 pk;
      pk[0] = f2b(xv.x); pk[1] = f2b(xv.y);
      pk[2] = f2b(xv.z); pk[3] = f2b(xv.w);
      *(u16x4*)&Xs[r][c] = pk;
    }
    __syncthreads();

    const unsigned short* wb = wall + t3 * 16384 + (w * 16 + ln) * 128 + 8 * g;
    bf16x8 bw[4];
    #pragma unroll
    for (int ks = 0; ks < 4; ++ks) bw[ks] = *(const bf16x8*)(wb + ks * 32);
    const float* bias = (t3 == 0) ? bq : (t3 == 1) ? bk : bv;
    float bval = bias[w * 16 + ln] * ((t3 == 0) ? 0.25f : 1.0f);

    f32x4 acc[4] = {};
    #pragma unroll
    for (int ks = 0; ks < 4; ++ks) {
      bf16x8 a[4];
      #pragma unroll
      for (int ms = 0; ms < 4; ++ms)
        a[ms] = *(const bf16x8*)&Xs[ms * 16 + ln][ks * 32 + 8 * g];
      #pragma unroll
      for (int ms = 0; ms < 4; ++ms)
        acc[ms] = __builtin_amdgcn_mfma_f32_16x16x32_bf16(a[ms], bw[ks],
                                                          acc[ms], 0, 0, 0);
    }
    __syncthreads();  // all Xs reads done before next-iter restage

    // D: col=ln (head dim d), row=4g+r within each 16-row subtile
    #pragma unroll
    for (int ms = 0; ms < 4; ++ms)
      #pragma unroll
      for (int r = 0; r < 4; ++r) {
        int l = ms * 16 + 4 * g + r;
        unsigned short hv = f2b(acc[ms][r] + bval);
        if (t3 == 0)      Qsh[w][l][ln] = hv;
        else if (t3 == 1) Ksh[w][l][ln] = hv;
        else              Vt[w][ln][l] = hv;   // V transposed: [d][t]
      }
  }
  // Q/K/V per-head tiles are own-wave; Ps[w] overlaps Xs but all Xs reads
  // finished at the last barrier -> safe to proceed without another barrier.

  // ---- QK^T swapped: s[tsub][lsub]; D col(ln)=l_local, row(4g+r)=t_local
  f32x4 s[4][4] = {};
  {
    bf16x8 z = zero8();
    bf16x8 aK[4], bQ[4];
    #pragma unroll
    for (int i = 0; i < 4; ++i) {
      aK[i] = (g < 2) ? *(const bf16x8*)&Ksh[w][i * 16 + ln][8 * g] : z;
      bQ[i] = (g < 2) ? *(const bf16x8*)&Qsh[w][i * 16 + ln][8 * g] : z;
    }
    #pragma unroll
    for (int t = 0; t < 4; ++t)
      #pragma unroll
      for (int l = 0; l < 4; ++l)
        s[t][l] = __builtin_amdgcn_mfma_f32_16x16x32_bf16(aK[t], bQ[l],
                                                          s[t][l], 0, 0, 0);
  }

  float mv[4][4];
  #pragma unroll
  for (int t = 0; t < 4; ++t)
    #pragma unroll
    for (int r = 0; r < 4; ++r) mv[t][r] = maskS[t * 16 + 4 * g + r];

  // softmax over t (rows) for each l-column this lane owns
  #pragma unroll
  for (int l = 0; l < 4; ++l) {
    float m = -INFINITY;
    #pragma unroll
    for (int t = 0; t < 4; ++t)
      #pragma unroll
      for (int r = 0; r < 4; ++r) {
        float sv = s[t][l][r] + mv[t][r];
        s[t][l][r] = sv;
        m = fmaxf(m, sv);
      }
    m = fmaxf(m, __shfl_xor(m, 16, 64));
    m = fmaxf(m, __shfl_xor(m, 32, 64));
    float sum = 0.f;
    #pragma unroll
    for (int t = 0; t < 4; ++t)
      #pragma unroll
      for (int r = 0; r < 4; ++r) {
        float p = (m == -INFINITY) ? 0.f : __expf(s[t][l][r] - m);
        s[t][l][r] = p;
        sum += p;
      }
    sum += __shfl_xor(sum, 16, 64);
    sum += __shfl_xor(sum, 32, 64);
    float inv = (sum > 0.f) ? 1.f / sum : 0.f;
    #pragma unroll
    for (int t = 0; t < 4; ++t)
      #pragma unroll
      for (int r = 0; r < 4; ++r) s[t][l][r] *= inv;
  }

  // P -> LDS bf16: Ps[w][l][t]
  #pragma unroll
  for (int t = 0; t < 4; ++t)
    #pragma unroll
    for (int l = 0; l < 4; ++l) {
      u16x4 pw;
      pw[0] = f2b(s[t][l][0]); pw[1] = f2b(s[t][l][1]);
      pw[2] = f2b(s[t][l][2]); pw[3] = f2b(s[t][l][3]);
      *(u16x4*)&Ps[w][l * 16 + ln][t * 16 + 4 * g] = pw;
    }

  // coalesced attn output write: (h,b,T,l,t) f32   (own-wave Ps, no barrier)
  {
    const long abase = ((long)w * NBT + bT) * 4096;
    #pragma unroll
    for (int it = 0; it < 16; ++it) {
      int row = it * 4 + g;
      u16x4 pv = *(const u16x4*)&Ps[w][row][4 * ln];
      float4 o = make_float4(b2f(pv[0]), b2f(pv[1]), b2f(pv[2]), b2f(pv[3]));
      *(float4*)&attn_out[abase + (long)row * 64 + 4 * ln] = o;
    }
  }

  // PV: O[l][d] = sum_t P[l][t] V[t][d]
  f32x4 oacc[4] = {};
  #pragma unroll
  for (int ks = 0; ks < 2; ++ks) {
    bf16x8 bV = *(const bf16x8*)&Vt[w][ln][ks * 32 + 8 * g];
    #pragma unroll
    for (int l = 0; l < 4; ++l) {
      bf16x8 aP = *(const bf16x8*)&Ps[w][l * 16 + ln][ks * 32 + 8 * g];
      oacc[l] = __builtin_amdgcn_mfma_f32_16x16x32_bf16(aP, bV, oacc[l],
                                                        0, 0, 0);
    }
  }

  __syncthreads();  // all Qsh/Ksh reads done -> Qbuf reusable as Oh

  // O head outputs -> Oh[64][136] row-major (col e = 16w+d)
  #pragma unroll
  for (int l = 0; l < 4; ++l)
    #pragma unroll
    for (int r = 0; r < 4; ++r)
      Oh[l * 16 + 4 * g + r][w * 16 + ln] = f2b(oacc[l][r]);

  __syncthreads();  // Oh complete (cross-wave read next)

  // ---- O projection: out0 = Oh @ Wo^T + bo ----
  {
    const unsigned short* wo = wall + 3 * 16384 + (w * 16 + ln) * 128 + 8 * g;
    bf16x8 bwo[4];
    #pragma unroll
    for (int ks = 0; ks < 4; ++ks) bwo[ks] = *(const bf16x8*)(wo + ks * 32);
    float bov = bo[w * 16 + ln];

    f32x4 acc[4] = {};
    #pragma unroll
    for (int ks = 0; ks < 4; ++ks) {
      bf16x8 a[4];
      #pragma unroll
      for (int ms = 0; ms < 4; ++ms)
        a[ms] = *(const bf16x8*)&Oh[ms * 16 + ln][ks * 32 + 8 * g];
      #pragma unroll
      for (int ms = 0; ms < 4; ++ms)
        acc[ms] = __builtin_amdgcn_mfma_f32_16x16x32_bf16(a[ms], bwo[ks],
                                                          acc[ms], 0, 0, 0);
    }
    #pragma unroll
    for (int ms = 0; ms < 4; ++ms)
      #pragma unroll
      for (int r = 0; r < 4; ++r)
        out0[(bT * 64 + ms * 16 + 4 * g + r) * 128 + w * 16 + ln] =
            acc[ms][r] + bov;
  }
}

// ---------------------------------------------------------------------------
extern "C" void kernel_launch(void* const* d_in, const int* in_sizes, int n_in,
                              void* d_out, int out_size, void* d_ws,
                              size_t ws_size, hipStream_t stream) {
  (void)in_sizes; (void)n_in; (void)out_size; (void)ws_size;
  const float* query = (const float*)d_in[0];
  const float* key   = (const float*)d_in[1];
  const float* value = (const float*)d_in[2];
  const unsigned char* mask = (const unsigned char*)d_in[3];
  const float* Wq = (const float*)d_in[4];
  const float* bq = (const float*)d_in[5];
  const float* Wk = (const float*)d_in[6];
  const float* bk = (const float*)d_in[7];
  const float* Wv = (const float*)d_in[8];
  const float* bv = (const float*)d_in[9];
  const float* Wo = (const float*)d_in[10];
  const float* bo = (const float*)d_in[11];

  float* out0 = (float*)d_out;
  float* attn_out = out0 + OUT0_ELEMS;

  char* ws = (char*)d_ws;
  int* flag = (int*)ws;
  unsigned short* wall = (unsigned short*)(ws + 256);  // 65536 bf16

  detect_mask_mode<<<1, 256, 0, stream>>>(mask, flag);
  prep_weights<<<256, 256, 0, stream>>>(Wq, Wk, Wv, Wo, wall);
  fused_kernel<<<NBT, 512, 0, stream>>>(query, key, value, mask, flag, wall,
                                        bq, bk, bv, bo, out0, attn_out);
}

// Round 3
// 120.920 us; speedup vs baseline: 1.3580x; 1.1412x over previous
//
#include <hip/hip_runtime.h>
#include <hip/hip_bf16.h>

// ---------------------------------------------------------------------------
// FactorizedAttention fused (N=32, T=50, LQ=LK=64, E=128, H=8, d=16)
// One block per (b,T) tile: QKV proj -> attention -> O proj.
// P and V stay entirely in registers via 16x16x16 MFMA fragment-layout match.
// LDS 65.3 KB -> 2 blocks/CU.
// out0: (N,T,LQ,E) f32 = 13107200 ; out1: attn (H,N,T,LQ,LK) f32 = 52428800
// ---------------------------------------------------------------------------

#define NBT 1600
#define OUT0_ELEMS 13107200L

typedef __attribute__((ext_vector_type(8))) short bf16x8;
typedef __attribute__((ext_vector_type(4))) short bf16x4;
typedef __attribute__((ext_vector_type(4))) float f32x4;
typedef __attribute__((ext_vector_type(4))) unsigned short u16x4;

__device__ __forceinline__ unsigned short f2b(float f) {
  union { float f; unsigned u; } v; v.f = f;
  unsigned r = v.u + 0x7FFFu + ((v.u >> 16) & 1u);
  return (unsigned short)(r >> 16);
}
__device__ __forceinline__ float b2f(unsigned short s) {
  union { unsigned u; float f; } v; v.u = ((unsigned)s) << 16;
  return v.f;
}
__device__ __forceinline__ bf16x4 pack4(f32x4 v) {
  bf16x4 r;
  r[0] = (short)f2b(v[0]); r[1] = (short)f2b(v[1]);
  r[2] = (short)f2b(v[2]); r[3] = (short)f2b(v[3]);
  return r;
}

#if defined(__has_builtin)
#if __has_builtin(__builtin_amdgcn_mfma_f32_16x16x16bf16_1k)
#define HAVE_MFMA16_1K 1
#endif
#endif

__device__ __forceinline__ f32x4 mfma16(bf16x4 a, bf16x4 b, f32x4 c) {
#ifdef HAVE_MFMA16_1K
  return __builtin_amdgcn_mfma_f32_16x16x16bf16_1k(a, b, c, 0, 0, 0);
#else
  f32x4 d;
  asm volatile("v_mfma_f32_16x16x16_bf16 %0, %1, %2, %3\n\ts_nop 7\n\ts_nop 7"
               : "=v"(d)
               : "v"(a), "v"(b), "v"(c));
  return d;
#endif
}

// ---------------------------------------------------------------------------
// Mask dtype detector (bool as int32 / bytes / f32). mode 0=int32,1=bytes,2=f32
// ---------------------------------------------------------------------------
__global__ void detect_mask_mode(const unsigned char* __restrict__ p,
                                 int* __restrict__ flag) {
  __shared__ int sb, sf;
  int t = threadIdx.x;
  if (t == 0) { sb = 0; sf = 0; }
  __syncthreads();
  int bnz = 0, fcnt = 0;
  for (int i = t * 16; i < t * 16 + 16; ++i)
    if ((i & 3) && p[i]) bnz++;
  const unsigned int* w = (const unsigned int*)p;
  for (int i = t * 4; i < t * 4 + 4; ++i)
    if (w[i] == 0x3f800000u) fcnt++;
  if (bnz) atomicAdd(&sb, 1);
  if (fcnt) atomicAdd(&sf, 1);
  __syncthreads();
  if (t == 0) *flag = sf ? 2 : (sb ? 1 : 0);
}

// ---------------------------------------------------------------------------
// Weights -> bf16 once (softmax scale 0.25 folded into Wq; exact, pow2).
// ---------------------------------------------------------------------------
__global__ void prep_weights(const float* __restrict__ Wq,
                             const float* __restrict__ Wk,
                             const float* __restrict__ Wv,
                             const float* __restrict__ Wo,
                             unsigned short* __restrict__ wall) {
  int idx = blockIdx.x * 256 + threadIdx.x;  // grid 256 -> 65536
  int m = idx >> 14, j = idx & 16383;
  const float* src = (m == 0) ? Wq : (m == 1) ? Wk : (m == 2) ? Wv : Wo;
  float s = (m == 0) ? 0.25f : 1.0f;
  wall[idx] = f2b(src[j] * s);
}

// ---------------------------------------------------------------------------
// Fused kernel: 1600 blocks x 512 threads (8 waves; wave w = head w).
// ---------------------------------------------------------------------------
__global__ __launch_bounds__(512, 4) void fused_kernel(
    const float* __restrict__ q_in, const float* __restrict__ k_in,
    const float* __restrict__ v_in, const unsigned char* __restrict__ maskp,
    const int* __restrict__ modeFlag, const unsigned short* __restrict__ wall,
    const float* __restrict__ bq, const float* __restrict__ bk,
    const float* __restrict__ bv, const float* __restrict__ bo,
    float* __restrict__ out0, float* __restrict__ attn_out) {
  __shared__ __align__(16) unsigned short Ksh[8][64][24];    // 24576 B
  __shared__ __align__(16) unsigned short Qbuf[8 * 64 * 24]; // 24576: Qsh|Oh
  __shared__ __align__(16) unsigned short Xs[64][136];       // 17408 B
  __shared__ float maskS[64];                                //   256 B

  auto Qsh = (unsigned short(*)[64][24])Qbuf;  // [8][64][24]
  auto Oh  = (unsigned short(*)[136])Qbuf;     // [64][136] (17408 <= 24576)

  const int tid = threadIdx.x;
  const int w = tid >> 6;           // wave = head
  const int lane = tid & 63;
  const int ln = lane & 15, g = lane >> 4;
  const long bT = blockIdx.x;

  // mask -> additive bias in LDS
  if (tid < 64) {
    int mode = *modeFlag;
    long midx = bT * 64 + tid;
    bool mk;
    if (mode == 0)      mk = ((const int*)maskp)[midx] != 0;
    else if (mode == 1) mk = maskp[midx] != 0;
    else                mk = ((const float*)maskp)[midx] != 0.0f;
    maskS[tid] = mk ? -INFINITY : 0.0f;
  }

  // prefetch the three 64x128 f32 X tiles into registers (4 float4 each)
  float4 xr[3][4];
  {
    const float* xs0 = q_in + bT * 8192;
    const float* xs1 = k_in + bT * 8192;
    const float* xs2 = v_in + bT * 8192;
    #pragma unroll
    for (int it = 0; it < 4; ++it) {
      int flat = it * 2048 + tid * 4;
      xr[0][it] = *(const float4*)(xs0 + flat);
      xr[1][it] = *(const float4*)(xs1 + flat);
      xr[2][it] = *(const float4*)(xs2 + flat);
    }
  }

  bf16x4 vk[4];  // V head tile, PV B-fragments (filled at t3==2)

  // ---- QKV projections: Y[:,16w..16w+16) per wave ----
  #pragma unroll
  for (int t3 = 0; t3 < 3; ++t3) {
    #pragma unroll
    for (int it = 0; it < 4; ++it) {
      int flat = it * 2048 + tid * 4;
      int r = flat >> 7, c = flat & 127;
      float4 xv = xr[t3][it];
      u16x4 pk;
      pk[0] = f2b(xv.x); pk[1] = f2b(xv.y);
      pk[2] = f2b(xv.z); pk[3] = f2b(xv.w);
      *(u16x4*)&Xs[r][c] = pk;
    }
    __syncthreads();

    const unsigned short* wb = wall + t3 * 16384 + (w * 16 + ln) * 128 + 8 * g;
    bf16x8 bw[4];
    #pragma unroll
    for (int ks = 0; ks < 4; ++ks) bw[ks] = *(const bf16x8*)(wb + ks * 32);
    const float* bias = (t3 == 0) ? bq : (t3 == 1) ? bk : bv;
    float bval = bias[w * 16 + ln] * ((t3 == 0) ? 0.25f : 1.0f);

    f32x4 acc[4] = {};
    #pragma unroll
    for (int ks = 0; ks < 4; ++ks) {
      bf16x8 a[4];
      #pragma unroll
      for (int ms = 0; ms < 4; ++ms)
        a[ms] = *(const bf16x8*)&Xs[ms * 16 + ln][ks * 32 + 8 * g];
      #pragma unroll
      for (int ms = 0; ms < 4; ++ms)
        acc[ms] = __builtin_amdgcn_mfma_f32_16x16x32_bf16(a[ms], bw[ks],
                                                          acc[ms], 0, 0, 0);
    }
    __syncthreads();  // all Xs reads done before next-iter restage

    // D: col=ln (head dim d), row=4g+r within each 16-row subtile
    #pragma unroll
    for (int ms = 0; ms < 4; ++ms) {
      if (t3 == 2) {
        f32x4 vb;
        #pragma unroll
        for (int r = 0; r < 4; ++r) vb[r] = acc[ms][r] + bval;
        vk[ms] = pack4(vb);  // V[t=16ms+4g+r][d=ln] -> PV B-frag, in-register
      } else {
        #pragma unroll
        for (int r = 0; r < 4; ++r) {
          int l = ms * 16 + 4 * g + r;
          unsigned short hv = f2b(acc[ms][r] + bval);
          if (t3 == 0) Qsh[w][l][ln] = hv;
          else         Ksh[w][l][ln] = hv;
        }
      }
    }
  }

  // ---- QK^T swapped via 16x16x16 (K = d = 16):
  // s[tsub][lsub]: lane holds S[t=16tsub+4g+r][l=16lsub+ln]
  f32x4 s[4][4] = {};
  {
    bf16x4 aK[4], bQ[4];
    #pragma unroll
    for (int i = 0; i < 4; ++i) {
      aK[i] = *(const bf16x4*)&Ksh[w][i * 16 + ln][4 * g];
      bQ[i] = *(const bf16x4*)&Qsh[w][i * 16 + ln][4 * g];
    }
    #pragma unroll
    for (int t = 0; t < 4; ++t)
      #pragma unroll
      for (int l = 0; l < 4; ++l)
        s[t][l] = mfma16(aK[t], bQ[l], s[t][l]);
  }

  float mv[4][4];
  #pragma unroll
  for (int t = 0; t < 4; ++t)
    #pragma unroll
    for (int r = 0; r < 4; ++r) mv[t][r] = maskS[t * 16 + 4 * g + r];

  // softmax over t (16 in-lane values + cross-g shfl) per l-column
  #pragma unroll
  for (int l = 0; l < 4; ++l) {
    float m = -INFINITY;
    #pragma unroll
    for (int t = 0; t < 4; ++t)
      #pragma unroll
      for (int r = 0; r < 4; ++r) {
        float sv = s[t][l][r] + mv[t][r];
        s[t][l][r] = sv;
        m = fmaxf(m, sv);
      }
    m = fmaxf(m, __shfl_xor(m, 16, 64));
    m = fmaxf(m, __shfl_xor(m, 32, 64));
    float sum = 0.f;
    #pragma unroll
    for (int t = 0; t < 4; ++t)
      #pragma unroll
      for (int r = 0; r < 4; ++r) {
        float p = (m == -INFINITY) ? 0.f : __expf(s[t][l][r] - m);
        s[t][l][r] = p;
        sum += p;
      }
    sum += __shfl_xor(sum, 16, 64);
    sum += __shfl_xor(sum, 32, 64);
    float inv = (sum > 0.f) ? 1.f / sum : 0.f;
    #pragma unroll
    for (int t = 0; t < 4; ++t)
      #pragma unroll
      for (int r = 0; r < 4; ++r) s[t][l][r] *= inv;
  }

  // attn output: direct f32 stores (exact P), then pack P -> PV A-fragments
  bf16x4 pa[4][4];  // [tsub][lsub]
  {
    const long abase = ((long)w * NBT + bT) * 4096;
    #pragma unroll
    for (int lsub = 0; lsub < 4; ++lsub) {
      long rowb = abase + (long)(lsub * 16 + ln) * 64;
      #pragma unroll
      for (int tsub = 0; tsub < 4; ++tsub) {
        *(f32x4*)&attn_out[rowb + tsub * 16 + 4 * g] = s[tsub][lsub];
        pa[tsub][lsub] = pack4(s[tsub][lsub]);
      }
    }
  }

  // PV in-register: O[l][d] = sum_t P[l][t] V[t][d]
  f32x4 oacc[4] = {};
  #pragma unroll
  for (int lsub = 0; lsub < 4; ++lsub)
    #pragma unroll
    for (int tsub = 0; tsub < 4; ++tsub)
      oacc[lsub] = mfma16(pa[tsub][lsub], vk[tsub], oacc[lsub]);

  __syncthreads();  // all Qsh reads done -> Qbuf reusable as Oh

  // O head outputs -> Oh[64][136] row-major (col e = 16w+d)
  #pragma unroll
  for (int lsub = 0; lsub < 4; ++lsub)
    #pragma unroll
    for (int r = 0; r < 4; ++r)
      Oh[lsub * 16 + 4 * g + r][w * 16 + ln] = f2b(oacc[lsub][r]);

  __syncthreads();  // Oh complete (cross-wave read next)

  // ---- O projection: out0 = Oh @ Wo^T + bo ----
  {
    const unsigned short* wo = wall + 3 * 16384 + (w * 16 + ln) * 128 + 8 * g;
    bf16x8 bwo[4];
    #pragma unroll
    for (int ks = 0; ks < 4; ++ks) bwo[ks] = *(const bf16x8*)(wo + ks * 32);
    float bov = bo[w * 16 + ln];

    f32x4 acc[4] = {};
    #pragma unroll
    for (int ks = 0; ks < 4; ++ks) {
      bf16x8 a[4];
      #pragma unroll
      for (int ms = 0; ms < 4; ++ms)
        a[ms] = *(const bf16x8*)&Oh[ms * 16 + ln][ks * 32 + 8 * g];
      #pragma unroll
      for (int ms = 0; ms < 4; ++ms)
        acc[ms] = __builtin_amdgcn_mfma_f32_16x16x32_bf16(a[ms], bwo[ks],
                                                          acc[ms], 0, 0, 0);
    }
    #pragma unroll
    for (int ms = 0; ms < 4; ++ms)
      #pragma unroll
      for (int r = 0; r < 4; ++r)
        out0[(bT * 64 + ms * 16 + 4 * g + r) * 128 + w * 16 + ln] =
            acc[ms][r] + bov;
  }
}

// ---------------------------------------------------------------------------
extern "C" void kernel_launch(void* const* d_in, const int* in_sizes, int n_in,
                              void* d_out, int out_size, void* d_ws,
                              size_t ws_size, hipStream_t stream) {
  (void)in_sizes; (void)n_in; (void)out_size; (void)ws_size;
  const float* query = (const float*)d_in[0];
  const float* key   = (const float*)d_in[1];
  const float* value = (const float*)d_in[2];
  const unsigned char* mask = (const unsigned char*)d_in[3];
  const float* Wq = (const float*)d_in[4];
  const float* bq = (const float*)d_in[5];
  const float* Wk = (const float*)d_in[6];
  const float* bk = (const float*)d_in[7];
  const float* Wv = (const float*)d_in[8];
  const float* bv = (const float*)d_in[9];
  const float* Wo = (const float*)d_in[10];
  const float* bo = (const float*)d_in[11];

  float* out0 = (float*)d_out;
  float* attn_out = out0 + OUT0_ELEMS;

  char* ws = (char*)d_ws;
  int* flag = (int*)ws;
  unsigned short* wall = (unsigned short*)(ws + 256);  // 65536 bf16

  detect_mask_mode<<<1, 256, 0, stream>>>(mask, flag);
  prep_weights<<<256, 256, 0, stream>>>(Wq, Wk, Wv, Wo, wall);
  fused_kernel<<<NBT, 512, 0, stream>>>(query, key, value, mask, flag, wall,
                                        bq, bk, bv, bo, out0, attn_out);
}